// Round 4
// baseline (121.500 us; speedup 1.0000x reference)
//
#include <hip/hip_runtime.h>

typedef __attribute__((ext_vector_type(8))) short bf16x8;
typedef __attribute__((ext_vector_type(4))) float f32x4;

#define SL 512
#define SLP 544               // padded seq rows per batch (rows 512..543 zero)
#define LN 100
#define MT 128                // t-rows per block
#define NTOT 320              // filter rows padded (300 real), 20 n-tiles
#define CH_USH (NTOT * 64)    // 20480 ush per (dc,p) chunk
#define NCH 40                // 8 dc * 5 p
#define A_ROWS 144
#define A_USH (A_ROWS * 64)   // 9216 ush
#define EMB_OFF ((size_t)NCH * CH_USH * 2)
#define EMB_BYTES ((size_t)64 * SLP * 512 * 2)
#define POOL_OFF (EMB_OFF + EMB_BYTES)

__device__ inline unsigned short f2bf(float x) {
    unsigned int u = __float_as_uint(x);
    u = u + 0x7FFFu + ((u >> 16) & 1u);   // RNE
    return (unsigned short)(u >> 16);
}
__device__ inline unsigned int pack2(float a, float b) {
    return (unsigned int)f2bf(a) | ((unsigned int)f2bf(b) << 16);
}
__device__ __forceinline__ void gload16(void* lds, const void* g) {
    __builtin_amdgcn_global_load_lds(
        (const __attribute__((address_space(1))) unsigned int*)g,
        (__attribute__((address_space(3))) unsigned int*)lds, 16, 0, 0);
}
#define WAITV(n) asm volatile("s_waitcnt vmcnt(" #n ")" ::: "memory")

// ---- filters f32 -> bf16, unified chunks [NCH][320 rows][64], zero-padded to
// w=5; source-side XOR swizzle (unit up holds logical u = up ^ (l&7)). Also
// zeroes the pooled buffer. ---------------------------------------------------
__global__ __launch_bounds__(256)
void cvt_filters(const float* __restrict__ f3, const float* __restrict__ f4,
                 const float* __restrict__ f5, unsigned short* __restrict__ fbf,
                 unsigned int* __restrict__ pooled) {
    int id = blockIdx.x * 256 + threadIdx.x;        // < 400*256 = 102400
    if (id < 64 * 300) pooled[id] = 0u;
    int c = id / 2560, r = id % 2560;               // chunk, unit-in-chunk
    int l = r >> 3, up = r & 7;
    int dc = c / 5, p = c % 5;
    int u = up ^ (l & 7);
    uint4 ov = make_uint4(0u, 0u, 0u, 0u);
    if (l < 300) {
        int wz = l / 100, li = l % 100, w = 3 + wz;
        if (p < w) {
            const float* src = (wz == 0) ? f3 : (wz == 1 ? f4 : f5);
            const float4* s4 = (const float4*)(src + (size_t)li * (w * 512) + p * 512 + dc * 64 + u * 8);
            float4 lo = s4[0], hi = s4[1];
            ov.x = pack2(lo.x, lo.y); ov.y = pack2(lo.z, lo.w);
            ov.z = pack2(hi.x, hi.y); ov.w = pack2(hi.z, hi.w);
        }
    }
    *(uint4*)(fbf + (size_t)c * CH_USH + l * 64 + up * 8) = ov;
}

// ---- gather + convert: embseq[b][t][d] bf16, zero rows for t >= SL ----------
__global__ __launch_bounds__(256)
void emb_gather(const int* __restrict__ words, const float* __restrict__ emb,
                unsigned short* __restrict__ embseq) {
    int r    = blockIdx.x * 4 + (threadIdx.x >> 6);   // < 64*SLP
    int lane = threadIdx.x & 63;
    int b    = r / SLP, t = r - b * SLP;
    uint4 ov = make_uint4(0u, 0u, 0u, 0u);
    if (t < SL) {
        int widx = words[b * SL + t];
        const float4* s4 = (const float4*)(emb + (size_t)widx * 512 + lane * 8);
        float4 lo = s4[0], hi = s4[1];
        ov.x = pack2(lo.x, lo.y); ov.y = pack2(lo.z, lo.w);
        ov.z = pack2(hi.x, hi.y); ov.w = pack2(hi.z, hi.w);
    }
    *(uint4*)(embseq + (size_t)r * 512 + lane * 8) = ov;
}

// ---- unified conv GEMM: M=128/block, N=320, K=2560; n-split waves -----------
__global__ __launch_bounds__(256, 1)
void conv_pool(const unsigned short* __restrict__ embseq,
               const unsigned short* __restrict__ fbf,
               const float* __restrict__ b3, const float* __restrict__ b4,
               const float* __restrict__ b5, unsigned int* __restrict__ pooled) {
    __shared__ __align__(16) unsigned short As[2 * A_USH];    // 36 KB
    __shared__ __align__(16) unsigned short Bs[3 * CH_USH];   // 120 KB
    const int b = blockIdx.y, t0 = blockIdx.x * MT;
    const int tid = threadIdx.x, lane = tid & 63, wv = tid >> 6;
    const unsigned short* embB = embseq + ((size_t)(b * SLP + t0)) * 512;

    auto stageB = [&](int chunk, int buf) {        // 2560 units, 10/thread
        const unsigned short* g = fbf + (size_t)chunk * CH_USH;
        unsigned short* dst = Bs + buf * CH_USH;
        #pragma unroll
        for (int j = 0; j < 10; ++j) {
            int k = tid + j * 256;
            gload16(dst + ((k >> 6) << 9), g + k * 8);
        }
    };
    auto stageA = [&](int dcv, int buf) {          // 1152 units, 5|4/thread
        unsigned short* dst = As + buf * A_USH;
        #pragma unroll
        for (int j = 0; j < 5; ++j) {
            int k = tid + j * 256;
            if (k < 1152) {
                int row = k >> 3, u = (k & 7) ^ (row & 7);
                gload16(dst + ((k >> 6) << 9),
                        embB + (size_t)row * 512 + dcv * 64 + u * 8);
            }
        }
    };

    stageA(0, 0);
    stageB(0, 0);

    f32x4 acc[8][5] = {};
    int cur = 0;

    #pragma unroll 1
    for (int dc = 0; dc < 8; ++dc) {
        const char* Ab = (const char*)(As + (dc & 1) * A_USH);
        #pragma unroll
        for (int p = 0; p < 5; ++p) {
            const int s = dc * 5 + p;
            int nxt = (cur == 2) ? 0 : cur + 1;
            if (p < 4) {
                stageB(s + 1, nxt);
                WAITV(10);                           // stage(s) retired
            } else if (dc < 7) {
                stageB(s + 1, nxt);
                stageA(dc + 1, (dc + 1) & 1);
                WAITV(14);                           // stage(s) retired, prefetch in flight
            } else {
                WAITV(0);                            // last phase
            }
            __builtin_amdgcn_s_barrier();
            __builtin_amdgcn_sched_barrier(0);

            const char* Bb = (const char*)(Bs + cur * CH_USH);
            #pragma unroll
            for (int kk = 0; kk < 2; ++kk) {
                const int kb2 = (kk << 6) + ((lane >> 4) << 4);
                bf16x8 a[8];
                #pragma unroll
                for (int m = 0; m < 8; ++m) {
                    int ar = (m << 4) + (lane & 15) + p;
                    a[m] = *(const bf16x8*)(Ab + ar * 128 + (kb2 ^ ((ar & 7) << 4)));
                }
                #pragma unroll
                for (int i = 0; i < 5; ++i) {
                    int l = ((wv * 5 + i) << 4) + (lane & 15);
                    bf16x8 bf = *(const bf16x8*)(Bb + l * 128 + (kb2 ^ ((l & 7) << 4)));
                    #pragma unroll
                    for (int m = 0; m < 8; ++m)
                        acc[m][i] = __builtin_amdgcn_mfma_f32_16x16x32_bf16(a[m], bf, acc[m][i], 0, 0, 0);
                }
            }
            cur = nxt;
        }
    }

    // epilogue: bias + relu + max over the block's 128 t rows, atomicMax merge
    #pragma unroll
    for (int i = 0; i < 5; ++i) {
        int l = ((wv * 5 + i) << 4) + (lane & 15);
        float bv;
        if (l < 100)       bv = b3[l];
        else if (l < 200)  bv = b4[l - 100];
        else if (l < 300)  bv = b5[l - 200];
        else               bv = 0.0f;
        float m = 0.0f;   // relu floor
        #pragma unroll
        for (int mt = 0; mt < 8; ++mt)
            #pragma unroll
            for (int j = 0; j < 4; ++j)
                m = fmaxf(m, acc[mt][i][j] + bv);
        m = fmaxf(m, __shfl_xor(m, 16));
        m = fmaxf(m, __shfl_xor(m, 32));
        if (lane < 16 && l < 300)
            atomicMax(&pooled[(size_t)b * 300 + l], __float_as_uint(m));
    }
}

// ---- final [64,300] x [300,10] ---------------------------------------------
__global__ __launch_bounds__(64)
void out_gemm(const unsigned int* __restrict__ pooled,
              const float* __restrict__ W, float* __restrict__ out) {
    int b = blockIdx.x;
    __shared__ float pshared[300];
    for (int i = threadIdx.x; i < 300; i += 64)
        pshared[i] = __uint_as_float(pooled[b * 300 + i]);
    __syncthreads();
    if (threadIdx.x < 10) {
        float s = 0.f;
        for (int c = 0; c < 300; ++c)
            s += pshared[c] * W[c * 10 + threadIdx.x];
        out[b * 10 + threadIdx.x] = s;
    }
}

extern "C" void kernel_launch(void* const* d_in, const int* in_sizes, int n_in,
                              void* d_out, int out_size, void* d_ws, size_t ws_size,
                              hipStream_t stream) {
    const int*   words = (const int*)d_in[0];
    const float* Emb   = (const float*)d_in[1];
    const float* outW  = (const float*)d_in[2];
    const float* f3    = (const float*)d_in[3];
    const float* b3    = (const float*)d_in[4];
    const float* f4    = (const float*)d_in[5];
    const float* b4    = (const float*)d_in[6];
    const float* f5    = (const float*)d_in[7];
    const float* b5    = (const float*)d_in[8];
    float* out = (float*)d_out;

    unsigned short* fbf    = (unsigned short*)d_ws;
    unsigned short* embseq = (unsigned short*)((char*)d_ws + EMB_OFF);
    unsigned int*   pooled = (unsigned int*)((char*)d_ws + POOL_OFF);

    cvt_filters<<<400, 256, 0, stream>>>(f3, f4, f5, fbf, pooled);
    emb_gather<<<(64 * SLP) / 4, 256, 0, stream>>>(words, Emb, embseq);
    conv_pool<<<dim3(SL / MT, 64), 256, 0, stream>>>(embseq, fbf, b3, b4, b5, pooled);
    out_gemm<<<64, 64, 0, stream>>>(pooled, outW, out);
}